// Round 4
// baseline (329.237 us; speedup 1.0000x reference)
//
#include <hip/hip_runtime.h>
#include <stdint.h>

typedef uint16_t u16;
typedef uint32_t u32;
typedef __bf16 bf16;
typedef bf16 bf16x8 __attribute__((ext_vector_type(8)));
typedef bf16 bf16x4 __attribute__((ext_vector_type(4)));
typedef float f32x4 __attribute__((ext_vector_type(4)));
typedef u16 u16x4 __attribute__((ext_vector_type(4)));

#define MFMA(a, b, c) __builtin_amdgcn_mfma_f32_16x16x32_bf16((a), (b), (c), 0, 0, 0)

#define BATCH 8
#define SEQ 1024
#define DMODEL 1024
#define NH 16
#define DK 64
#define LOG2E 1.4426950408889634f

// HW bf16 convert (RNE): gfx950 selects v_cvt_pk_bf16_f32 for fptrunc
__device__ __forceinline__ u16 bfbits(float f) {
    bf16 h = (bf16)f;
    return __builtin_bit_cast(u16, h);
}

// raw v_exp_f32 (args bounded |x|<~45 here; skip libm's range-guard sequence)
__device__ __forceinline__ float exp2_raw(float x) {
    float r;
    asm("v_exp_f32 %0, %1" : "=v"(r) : "v"(x));
    return r;
}

// async global->LDS, 16B per lane; LDS dst = wave-uniform base + lane*16
__device__ __forceinline__ void gload_lds16(const u16* g, u16* l) {
    __builtin_amdgcn_global_load_lds(
        (__attribute__((address_space(1))) void*)g,
        (__attribute__((address_space(3))) void*)l, 16, 0, 0);
}

// ---------------- merged prep: x->bf16, W->bf16^T, F4 bias table ----------------
// blocks [0,8192): convert x; [8192,9216): transpose-convert weights (64x64 tiles);
// [9216,9344): F4 bias. Branch is block-uniform; __syncthreads only in wt branch.
__global__ __launch_bounds__(256) void prep_kernel(
        const float* __restrict__ x, const float* __restrict__ W0,
        const float* __restrict__ W1, const float* __restrict__ W2,
        const float* __restrict__ W3, const float* __restrict__ rel_emb,
        u16* __restrict__ xb, u16* __restrict__ T0, u16* __restrict__ T1,
        u16* __restrict__ T2, u16* __restrict__ T3, f32x4* __restrict__ F4) {
    __shared__ u16 Ts[64 * 72];        // wt branch only
    const int bid = blockIdx.x, tid = threadIdx.x;
    if (bid < 8192) {
        size_t id = (size_t)bid * 256 + tid;
        f32x4 v = *(const f32x4*)(x + id * 4);
        bf16x4 o;
        o[0] = (bf16)v[0]; o[1] = (bf16)v[1]; o[2] = (bf16)v[2]; o[3] = (bf16)v[3];
        *(bf16x4*)(xb + id * 4) = o;
    } else if (bid < 9216) {
        const int t = bid - 8192;
        const int z = t >> 8, rem = t & 255;
        const float* W = (z == 0) ? W0 : (z == 1) ? W1 : (z == 2) ? W2 : W3;
        u16* T = (z == 0) ? T0 : (z == 1) ? T1 : (z == 2) ? T2 : T3;
        const int k0 = (rem >> 4) * 64, n0 = (rem & 15) * 64;
        const int r16 = tid >> 4, c0 = (tid & 15) * 4;
        #pragma unroll
        for (int rr = 0; rr < 4; rr++) {
            int r = rr * 16 + r16;     // k-row within tile
            f32x4 vv = *(const f32x4*)&W[(size_t)(k0 + r) * 1024 + n0 + c0];
            #pragma unroll
            for (int i = 0; i < 4; i++) Ts[(c0 + i) * 72 + r] = bfbits(vv[i]);
        }
        __syncthreads();
        int n = tid >> 2, seg = (tid & 3) * 16;
        *(bf16x8*)&T[(size_t)(n0 + n) * 1024 + k0 + seg] = *(const bf16x8*)&Ts[n * 72 + seg];
        *(bf16x8*)&T[(size_t)(n0 + n) * 1024 + k0 + seg + 8] =
            *(const bf16x8*)&Ts[n * 72 + seg + 8];
    } else {
        int id = (bid - 9216) * 256 + tid;
        if (id >= NH * 2047) return;
        int h = id / 2047, tt0 = id % 2047;
        f32x4 o;
        #pragma unroll
        for (int j = 0; j < 4; j++) {
            int tt = tt0 + j;
            float val = 0.f;
            if (tt <= 2046) {
                int rel = tt - 1023;
                int n = -rel;
                int b = 0;
                if (n < 0) { b = 16; n = -n; }
                int v;
                if (n < 8) {
                    v = n;
                } else {
                    int e = 31 - __clz(n);
                    int f = 2 * e + ((unsigned)(n * n) >= (1u << (2 * e + 1)) ? 1 : 0);
                    v = min(2 + f, 15);
                }
                val = LOG2E * rel_emb[(b + v) * NH + h];
            }
            o[j] = val;
        }
        F4[(size_t)h * 2047 + tt0] = o;
    }
}

// ---------------- QKV projection GEMM (R0 2-phase 128^2, known 70.4 us) ----------
// 8-phase 256^2 arc (R1/R2) abandoned: this problem's grid is 384 tiles on 256 CUs
// at 1 block/CU -> 1.5 ragged rounds (x0.75) + K=1024 short-loop overhead; measured
// 73-94 us vs this kernel's 70.4. The 2-phase 128^2 runs ~3 blocks/CU where
// cross-block wave overlap hides the barrier drains (m97/m114 mechanism).
__global__ __launch_bounds__(256) void gemm_qkv_kernel(
        const u16* __restrict__ xb,
        const u16* __restrict__ Wqt, const u16* __restrict__ Wkt, const u16* __restrict__ Wvt,
        u16* __restrict__ qb, u16* __restrict__ kb, u16* __restrict__ vb) {
    __shared__ u16 As[8192];       // 2 panels of 128x32
    __shared__ u16 Bs[8192];
    const int z = blockIdx.y >> 3;
    const u16* Bt = (z == 0) ? Wqt : (z == 1) ? Wkt : Wvt;
    const int m0 = blockIdx.x * 128, n0 = (blockIdx.y & 7) * 128;
    const int tid = threadIdx.x, w = tid >> 6, lane = tid & 63;
    const int quad = lane >> 4, l16 = lane & 15;
    const int rw = w >> 1, cw = w & 1;
    const int srow = lane >> 2, sseg = lane & 3;   // lane covers row base+srow, 16B seg

    f32x4 acc[4][4];
    #pragma unroll
    for (int i = 0; i < 4; i++)
        #pragma unroll
        for (int j = 0; j < 4; j++) acc[i][j] = (f32x4){0.f, 0.f, 0.f, 0.f};

    for (int kk = 0; kk < 1024; kk += 64) {
        __syncthreads();
        #pragma unroll
        for (int p = 0; p < 2; p++) {
            #pragma unroll
            for (int r = 0; r < 2; r++) {
                int base = r * 64 + w * 16;
                int row = base + srow;
                gload_lds16(&xb[(size_t)(m0 + row) * 1024 + kk + p * 32 + sseg * 8],
                            &As[p * 4096 + base * 32]);
                gload_lds16(&Bt[(size_t)(n0 + row) * 1024 + kk + p * 32 + sseg * 8],
                            &Bs[p * 4096 + base * 32]);
            }
        }
        __syncthreads();
        #pragma unroll
        for (int p = 0; p < 2; p++) {
            bf16x8 af[4], bfr[4];
            #pragma unroll
            for (int mt = 0; mt < 4; mt++)
                af[mt] = *(const bf16x8*)&As[p * 4096 + (rw * 64 + mt * 16 + l16) * 32 + quad * 8];
            #pragma unroll
            for (int nt = 0; nt < 4; nt++)
                bfr[nt] = *(const bf16x8*)&Bs[p * 4096 + (cw * 64 + nt * 16 + l16) * 32 + quad * 8];
            #pragma unroll
            for (int mt = 0; mt < 4; mt++)
                #pragma unroll
                for (int nt = 0; nt < 4; nt++)
                    acc[mt][nt] = MFMA(af[mt], bfr[nt], acc[mt][nt]);
        }
    }

    #pragma unroll
    for (int mt = 0; mt < 4; mt++) {
        int gmBase = m0 + rw * 64 + mt * 16 + quad * 4;
        #pragma unroll
        for (int nt = 0; nt < 4; nt++) {
            int gn = n0 + cw * 64 + nt * 16 + l16;
            int h = gn >> 6, dk = gn & 63;
            if (z == 2) {
                // V^T store: s = gmBase..+3 consecutive -> one u16x4
                int b_ = gmBase >> 10, s0 = gmBase & 1023;
                u16x4 pk = { bfbits(acc[mt][nt][0]), bfbits(acc[mt][nt][1]),
                             bfbits(acc[mt][nt][2]), bfbits(acc[mt][nt][3]) };
                *(u16x4*)&vb[(((size_t)b_ * NH + h) * DK + dk) * SEQ + s0] = pk;
            } else {
                u16* o = z ? kb : qb;
                #pragma unroll
                for (int r = 0; r < 4; r++) {
                    int gm = gmBase + r;
                    int b_ = gm >> 10, s = gm & 1023;
                    float sv = acc[mt][nt][r];
                    if (z == 0) sv *= LOG2E;       // fold exp2 scale into Q
                    o[(((size_t)b_ * NH + h) * SEQ + s) * DK + dk] = bfbits(sv);
                }
            }
        }
    }
}

// ---------------- output projection GEMM (x = m0 swizzle, BK=64 panels) ------------
__global__ __launch_bounds__(256) void gemm_out_kernel(
        const u16* __restrict__ ctx, const u16* __restrict__ Wot, float* __restrict__ out) {
    __shared__ u16 As[8192];
    __shared__ u16 Bs[8192];
    const int m0 = blockIdx.x * 128, n0 = blockIdx.y * 128;
    const int tid = threadIdx.x, w = tid >> 6, lane = tid & 63;
    const int quad = lane >> 4, l16 = lane & 15;
    const int rw = w >> 1, cw = w & 1;
    const int srow = lane >> 2, sseg = lane & 3;

    f32x4 acc[4][4];
    #pragma unroll
    for (int i = 0; i < 4; i++)
        #pragma unroll
        for (int j = 0; j < 4; j++) acc[i][j] = (f32x4){0.f, 0.f, 0.f, 0.f};

    for (int kk = 0; kk < 1024; kk += 64) {
        __syncthreads();
        #pragma unroll
        for (int p = 0; p < 2; p++) {
            #pragma unroll
            for (int r = 0; r < 2; r++) {
                int base = r * 64 + w * 16;
                int row = base + srow;
                gload_lds16(&ctx[(size_t)(m0 + row) * 1024 + kk + p * 32 + sseg * 8],
                            &As[p * 4096 + base * 32]);
                gload_lds16(&Wot[(size_t)(n0 + row) * 1024 + kk + p * 32 + sseg * 8],
                            &Bs[p * 4096 + base * 32]);
            }
        }
        __syncthreads();
        #pragma unroll
        for (int p = 0; p < 2; p++) {
            bf16x8 af[4], bfr[4];
            #pragma unroll
            for (int mt = 0; mt < 4; mt++)
                af[mt] = *(const bf16x8*)&As[p * 4096 + (rw * 64 + mt * 16 + l16) * 32 + quad * 8];
            #pragma unroll
            for (int nt = 0; nt < 4; nt++)
                bfr[nt] = *(const bf16x8*)&Bs[p * 4096 + (cw * 64 + nt * 16 + l16) * 32 + quad * 8];
            #pragma unroll
            for (int mt = 0; mt < 4; mt++)
                #pragma unroll
                for (int nt = 0; nt < 4; nt++)
                    acc[mt][nt] = MFMA(af[mt], bfr[nt], acc[mt][nt]);
        }
    }

    #pragma unroll
    for (int mt = 0; mt < 4; mt++) {
        int gmBase = m0 + rw * 64 + mt * 16 + quad * 4;
        #pragma unroll
        for (int nt = 0; nt < 4; nt++) {
            int gn = n0 + cw * 64 + nt * 16 + l16;
            #pragma unroll
            for (int r = 0; r < 4; r++)
                out[(size_t)(gmBase + r) * 1024 + gn] = acc[mt][nt][r];
        }
    }
}

// ---------------- fused attention: S^T, fixed-max flash, NO K/V LDS staging -------
// R4 (Common-mistake #7 / m169): K and V for one head are 128 KB each and L2-resident
// (all 8 q-tile blocks of a head land on one XCD: id%8 == bh%8). LDS-staging them was
// pure overhead: 2 barriers/k-tile (32 lockstep drains/block), staging stores,
// prefetch registers. Now MFMA operands load DIRECTLY from global (L2-hot):
//   K frag: wave covers 16 rows x 64B contiguous segments (coalesced);
//   V^T frag: 16 rows (stride 2KB) x 64B segments (coalesced).
// Zero __syncthreads remain; only wave-private Pt (transpose buffer) uses LDS.
// 4 fully-independent waves/block -> TLP hides L2 latency; setprio pays (m191 regime).
__global__ __launch_bounds__(256) void attn_kernel(
        const u16* __restrict__ qb, const u16* __restrict__ kb,
        const u16* __restrict__ vb, const f32x4* __restrict__ F4,
        u16* __restrict__ ctx) {
    __shared__ u16 Pt[4][32 * 40];     // per-wave P^T buffer, stride 40  10240 B
    const int bh = blockIdx.x;
    const int h = bh & (NH - 1), b_ = bh >> 4;
    const int tid = threadIdx.x, w = tid >> 6, lane = tid & 63;
    const int quad = lane >> 4, l16 = lane & 15;
    const int q0 = blockIdx.y * 128 + w * 32;

    const f32x4* F4h = F4 + (size_t)h * 2047;
    // saturated-bucket constants: rel <= -91 -> bucket 15; rel >= +91 -> bucket 31
    const float cL = F4h[0][0];        // val(rel = -1023)
    const float cR = F4h[2046][0];     // val(rel = +1023)

    // Q fragments (B-operand layout): bq[mt][c] = Q[q0+mt*16+l16][c*32+quad*8 ..+7]
    bf16x8 bq[2][2];
    #pragma unroll
    for (int mt = 0; mt < 2; mt++) {
        const u16* qrow = qb + ((size_t)bh * SEQ + q0 + mt * 16 + l16) * DK;
        bq[mt][0] = *(const bf16x8*)(qrow + quad * 8);
        bq[mt][1] = *(const bf16x8*)(qrow + 32 + quad * 8);
    }

    float l_[2] = {0.f, 0.f};          // lane-partial row sums (this quad's k only)
    f32x4 oacc[2][4];                  // O^T frags [mt][dt]
    #pragma unroll
    for (int mt = 0; mt < 2; mt++)
        #pragma unroll
        for (int dt = 0; dt < 4; dt++) oacc[mt][dt] = (f32x4){0.f, 0.f, 0.f, 0.f};

    const u16* kbase_p = kb + (size_t)bh * SEQ * DK;
    const u16* vbase_p = vb + (size_t)bh * DK * SEQ;

    for (int kt = 0; kt < 16; kt++) {
        const int kbase = kt * 64;

        // S^T = K·Q^T + bias (bias via accumulator init, log2 domain)
        f32x4 sc[2][4];
        // wave-uniform far-tile test: whole tile saturated on one side
        if (kbase <= q0 - 191 || kbase >= q0 + 159) {
            const float cc = (kbase < q0) ? cL : cR;
            #pragma unroll
            for (int mt = 0; mt < 2; mt++)
                #pragma unroll
                for (int nt = 0; nt < 4; nt++)
                    sc[mt][nt] = (f32x4){cc, cc, cc, cc};
        } else {
            #pragma unroll
            for (int mt = 0; mt < 2; mt++)
                #pragma unroll
                for (int nt = 0; nt < 4; nt++) {
                    int t0 = (kbase + nt * 16 + quad * 4) - (q0 + mt * 16 + l16) + 1023;
                    sc[mt][nt] = F4h[t0];
                }
        }

        // QK^T: K fragments straight from global (L2-hot)
        __builtin_amdgcn_s_setprio(1);
        #pragma unroll
        for (int nt = 0; nt < 4; nt++) {
            const u16* krow = kbase_p + (size_t)(kbase + nt * 16 + l16) * DK;
            bf16x8 ak0 = *(const bf16x8*)(krow + quad * 8);
            bf16x8 ak1 = *(const bf16x8*)(krow + 32 + quad * 8);
            #pragma unroll
            for (int mt = 0; mt < 2; mt++) {
                sc[mt][nt] = MFMA(ak0, bq[mt][0], sc[mt][nt]);
                sc[mt][nt] = MFMA(ak1, bq[mt][1], sc[mt][nt]);
            }
        }
        __builtin_amdgcn_s_setprio(0);

        // exp2, pack P^T, PV — per k-half (wave-private Pt buffer, no barriers)
        #pragma unroll
        for (int c = 0; c < 2; c++) {
            #pragma unroll
            for (int mt = 0; mt < 2; mt++) {
                #pragma unroll
                for (int i = 0; i < 2; i++) {
                    int nt = 2 * c + i;
                    float p0 = exp2_raw(sc[mt][nt][0]);
                    float p1 = exp2_raw(sc[mt][nt][1]);
                    float p2 = exp2_raw(sc[mt][nt][2]);
                    float p3 = exp2_raw(sc[mt][nt][3]);
                    l_[mt] += (p0 + p1) + (p2 + p3);
                    bf16x4 pk;
                    pk[0] = (bf16)p0; pk[1] = (bf16)p1;
                    pk[2] = (bf16)p2; pk[3] = (bf16)p3;
                    *(bf16x4*)&Pt[w][(mt * 16 + l16) * 40 + i * 16 + quad * 4] = pk;
                }
            }
            // O^T += V^T · P^T for this k-half; V^T frags straight from global
            bf16x8 bp[2];
            #pragma unroll
            for (int mt = 0; mt < 2; mt++)
                bp[mt] = *(const bf16x8*)&Pt[w][(mt * 16 + l16) * 40 + quad * 8];
            __builtin_amdgcn_s_setprio(1);
            #pragma unroll
            for (int dt = 0; dt < 4; dt++) {
                const u16* vrow = vbase_p + (size_t)(dt * 16 + l16) * SEQ + kbase + c * 32;
                bf16x8 av = *(const bf16x8*)(vrow + quad * 8);
                #pragma unroll
                for (int mt = 0; mt < 2; mt++)
                    oacc[mt][dt] = MFMA(av, bp[mt], oacc[mt][dt]);
            }
            __builtin_amdgcn_s_setprio(0);
        }
    }

    // epilogue: reduce l across quads (k-partials), normalize, write ctx
    #pragma unroll
    for (int mt = 0; mt < 2; mt++) {
        float l = l_[mt];
        l += __shfl_xor(l, 16, 64);
        l += __shfl_xor(l, 32, 64);
        float inv = 1.f / l;
        int gq = q0 + mt * 16 + l16;
        #pragma unroll
        for (int dt = 0; dt < 4; dt++) {
            u16x4 pk = { bfbits(oacc[mt][dt][0] * inv), bfbits(oacc[mt][dt][1] * inv),
                         bfbits(oacc[mt][dt][2] * inv), bfbits(oacc[mt][dt][3] * inv) };
            *(u16x4*)&ctx[((size_t)b_ * SEQ + gq) * DMODEL + h * DK + dt * 16 + quad * 4] = pk;
        }
    }
}

extern "C" void kernel_launch(void* const* d_in, const int* in_sizes, int n_in,
                              void* d_out, int out_size, void* d_ws, size_t ws_size,
                              hipStream_t stream) {
    const float* x   = (const float*)d_in[0];
    const float* Wq  = (const float*)d_in[1];
    const float* Wk  = (const float*)d_in[2];
    const float* Wv  = (const float*)d_in[3];
    const float* Wo  = (const float*)d_in[4];
    const float* rel = (const float*)d_in[5];
    float* out = (float*)d_out;

    char* p = (char*)d_ws;
    u16* xb  = (u16*)p; p += (size_t)BATCH * SEQ * DMODEL * 2;   // 16 MB
    u16* Wqt = (u16*)p; p += (size_t)DMODEL * DMODEL * 2;        // 2 MB each
    u16* Wkt = (u16*)p; p += (size_t)DMODEL * DMODEL * 2;
    u16* Wvt = (u16*)p; p += (size_t)DMODEL * DMODEL * 2;
    u16* Wot = (u16*)p; p += (size_t)DMODEL * DMODEL * 2;
    u16* qb  = (u16*)p; p += (size_t)BATCH * NH * SEQ * DK * 2;  // 16 MB each
    u16* kb  = (u16*)p; p += (size_t)BATCH * NH * SEQ * DK * 2;
    u16* vb  = (u16*)p; p += (size_t)BATCH * NH * SEQ * DK * 2;
    u16* ctx = (u16*)p; p += (size_t)BATCH * SEQ * DMODEL * 2;
    f32x4* F4 = (f32x4*)p; p += (size_t)NH * 2047 * 16;          // 0.5 MB

    // merged prep: converts + bias table in one launch
    prep_kernel<<<9344, 256, 0, stream>>>(x, Wq, Wk, Wv, Wo, rel,
                                          xb, Wqt, Wkt, Wvt, Wot, F4);

    // grid x = m0: per-XCD A-tile residency
    gemm_qkv_kernel<<<dim3(64, 24), 256, 0, stream>>>(xb, Wqt, Wkt, Wvt, qb, kb, vb);

    attn_kernel<<<dim3(128, 8), 256, 0, stream>>>(qb, kb, vb, F4, ctx);

    gemm_out_kernel<<<dim3(64, 8), 256, 0, stream>>>(ctx, Wot, out);
}

// Round 5
// 236.709 us; speedup vs baseline: 1.3909x; 1.3909x over previous
//
#include <hip/hip_runtime.h>
#include <stdint.h>

typedef uint16_t u16;
typedef uint32_t u32;
typedef __bf16 bf16;
typedef bf16 bf16x8 __attribute__((ext_vector_type(8)));
typedef bf16 bf16x4 __attribute__((ext_vector_type(4)));
typedef float f32x4 __attribute__((ext_vector_type(4)));
typedef u16 u16x4 __attribute__((ext_vector_type(4)));

#define MFMA(a, b, c) __builtin_amdgcn_mfma_f32_16x16x32_bf16((a), (b), (c), 0, 0, 0)

#define BATCH 8
#define SEQ 1024
#define DMODEL 1024
#define NH 16
#define DK 64
#define LOG2E 1.4426950408889634f

// HW bf16 convert (RNE): gfx950 selects v_cvt_pk_bf16_f32 for fptrunc
__device__ __forceinline__ u16 bfbits(float f) {
    bf16 h = (bf16)f;
    return __builtin_bit_cast(u16, h);
}

// raw v_exp_f32 (args bounded |x|<~45 here; skip libm's range-guard sequence)
__device__ __forceinline__ float exp2_raw(float x) {
    float r;
    asm("v_exp_f32 %0, %1" : "=v"(r) : "v"(x));
    return r;
}

// async global->LDS, 16B per lane; LDS dst = wave-uniform base + lane*16
__device__ __forceinline__ void gload_lds16(const u16* g, u16* l) {
    __builtin_amdgcn_global_load_lds(
        (__attribute__((address_space(1))) void*)g,
        (__attribute__((address_space(3))) void*)l, 16, 0, 0);
}

// ---------------- merged prep: x->bf16, W->bf16^T, F4 bias table ----------------
// blocks [0,8192): convert x; [8192,9216): transpose-convert weights (64x64 tiles);
// [9216,9344): F4 bias. Branch is block-uniform; __syncthreads only in wt branch.
__global__ __launch_bounds__(256) void prep_kernel(
        const float* __restrict__ x, const float* __restrict__ W0,
        const float* __restrict__ W1, const float* __restrict__ W2,
        const float* __restrict__ W3, const float* __restrict__ rel_emb,
        u16* __restrict__ xb, u16* __restrict__ T0, u16* __restrict__ T1,
        u16* __restrict__ T2, u16* __restrict__ T3, f32x4* __restrict__ F4) {
    __shared__ u16 Ts[64 * 72];        // wt branch only
    const int bid = blockIdx.x, tid = threadIdx.x;
    if (bid < 8192) {
        size_t id = (size_t)bid * 256 + tid;
        f32x4 v = *(const f32x4*)(x + id * 4);
        bf16x4 o;
        o[0] = (bf16)v[0]; o[1] = (bf16)v[1]; o[2] = (bf16)v[2]; o[3] = (bf16)v[3];
        *(bf16x4*)(xb + id * 4) = o;
    } else if (bid < 9216) {
        const int t = bid - 8192;
        const int z = t >> 8, rem = t & 255;
        const float* W = (z == 0) ? W0 : (z == 1) ? W1 : (z == 2) ? W2 : W3;
        u16* T = (z == 0) ? T0 : (z == 1) ? T1 : (z == 2) ? T2 : T3;
        const int k0 = (rem >> 4) * 64, n0 = (rem & 15) * 64;
        const int r16 = tid >> 4, c0 = (tid & 15) * 4;
        #pragma unroll
        for (int rr = 0; rr < 4; rr++) {
            int r = rr * 16 + r16;     // k-row within tile
            f32x4 vv = *(const f32x4*)&W[(size_t)(k0 + r) * 1024 + n0 + c0];
            #pragma unroll
            for (int i = 0; i < 4; i++) Ts[(c0 + i) * 72 + r] = bfbits(vv[i]);
        }
        __syncthreads();
        int n = tid >> 2, seg = (tid & 3) * 16;
        *(bf16x8*)&T[(size_t)(n0 + n) * 1024 + k0 + seg] = *(const bf16x8*)&Ts[n * 72 + seg];
        *(bf16x8*)&T[(size_t)(n0 + n) * 1024 + k0 + seg + 8] =
            *(const bf16x8*)&Ts[n * 72 + seg + 8];
    } else {
        int id = (bid - 9216) * 256 + tid;
        if (id >= NH * 2047) return;
        int h = id / 2047, tt0 = id % 2047;
        f32x4 o;
        #pragma unroll
        for (int j = 0; j < 4; j++) {
            int tt = tt0 + j;
            float val = 0.f;
            if (tt <= 2046) {
                int rel = tt - 1023;
                int n = -rel;
                int b = 0;
                if (n < 0) { b = 16; n = -n; }
                int v;
                if (n < 8) {
                    v = n;
                } else {
                    int e = 31 - __clz(n);
                    int f = 2 * e + ((unsigned)(n * n) >= (1u << (2 * e + 1)) ? 1 : 0);
                    v = min(2 + f, 15);
                }
                val = LOG2E * rel_emb[(b + v) * NH + h];
            }
            o[j] = val;
        }
        F4[(size_t)h * 2047 + tt0] = o;
    }
}

// ---------------- QKV projection GEMM (R0 2-phase 128^2, known 70.4 us) ----------
// 8-phase 256^2 arc (R1/R2) abandoned: this problem's grid is 384 tiles on 256 CUs
// at 1 block/CU -> 1.5 ragged rounds (x0.75) + K=1024 short-loop overhead; measured
// 73-94 us vs this kernel's 70.4. The 2-phase 128^2 runs ~3 blocks/CU where
// cross-block wave overlap hides the barrier drains (m97/m114 mechanism).
__global__ __launch_bounds__(256) void gemm_qkv_kernel(
        const u16* __restrict__ xb,
        const u16* __restrict__ Wqt, const u16* __restrict__ Wkt, const u16* __restrict__ Wvt,
        u16* __restrict__ qb, u16* __restrict__ kb, u16* __restrict__ vb) {
    __shared__ u16 As[8192];       // 2 panels of 128x32
    __shared__ u16 Bs[8192];
    const int z = blockIdx.y >> 3;
    const u16* Bt = (z == 0) ? Wqt : (z == 1) ? Wkt : Wvt;
    const int m0 = blockIdx.x * 128, n0 = (blockIdx.y & 7) * 128;
    const int tid = threadIdx.x, w = tid >> 6, lane = tid & 63;
    const int quad = lane >> 4, l16 = lane & 15;
    const int rw = w >> 1, cw = w & 1;
    const int srow = lane >> 2, sseg = lane & 3;   // lane covers row base+srow, 16B seg

    f32x4 acc[4][4];
    #pragma unroll
    for (int i = 0; i < 4; i++)
        #pragma unroll
        for (int j = 0; j < 4; j++) acc[i][j] = (f32x4){0.f, 0.f, 0.f, 0.f};

    for (int kk = 0; kk < 1024; kk += 64) {
        __syncthreads();
        #pragma unroll
        for (int p = 0; p < 2; p++) {
            #pragma unroll
            for (int r = 0; r < 2; r++) {
                int base = r * 64 + w * 16;
                int row = base + srow;
                gload_lds16(&xb[(size_t)(m0 + row) * 1024 + kk + p * 32 + sseg * 8],
                            &As[p * 4096 + base * 32]);
                gload_lds16(&Bt[(size_t)(n0 + row) * 1024 + kk + p * 32 + sseg * 8],
                            &Bs[p * 4096 + base * 32]);
            }
        }
        __syncthreads();
        #pragma unroll
        for (int p = 0; p < 2; p++) {
            bf16x8 af[4], bfr[4];
            #pragma unroll
            for (int mt = 0; mt < 4; mt++)
                af[mt] = *(const bf16x8*)&As[p * 4096 + (rw * 64 + mt * 16 + l16) * 32 + quad * 8];
            #pragma unroll
            for (int nt = 0; nt < 4; nt++)
                bfr[nt] = *(const bf16x8*)&Bs[p * 4096 + (cw * 64 + nt * 16 + l16) * 32 + quad * 8];
            #pragma unroll
            for (int mt = 0; mt < 4; mt++)
                #pragma unroll
                for (int nt = 0; nt < 4; nt++)
                    acc[mt][nt] = MFMA(af[mt], bfr[nt], acc[mt][nt]);
        }
    }

    #pragma unroll
    for (int mt = 0; mt < 4; mt++) {
        int gmBase = m0 + rw * 64 + mt * 16 + quad * 4;
        #pragma unroll
        for (int nt = 0; nt < 4; nt++) {
            int gn = n0 + cw * 64 + nt * 16 + l16;
            int h = gn >> 6, dk = gn & 63;
            if (z == 2) {
                // V^T store: s = gmBase..+3 consecutive -> one u16x4
                int b_ = gmBase >> 10, s0 = gmBase & 1023;
                u16x4 pk = { bfbits(acc[mt][nt][0]), bfbits(acc[mt][nt][1]),
                             bfbits(acc[mt][nt][2]), bfbits(acc[mt][nt][3]) };
                *(u16x4*)&vb[(((size_t)b_ * NH + h) * DK + dk) * SEQ + s0] = pk;
            } else {
                u16* o = z ? kb : qb;
                #pragma unroll
                for (int r = 0; r < 4; r++) {
                    int gm = gmBase + r;
                    int b_ = gm >> 10, s = gm & 1023;
                    float sv = acc[mt][nt][r];
                    if (z == 0) sv *= LOG2E;       // fold exp2 scale into Q
                    o[(((size_t)b_ * NH + h) * SEQ + s) * DK + dk] = bfbits(sv);
                }
            }
        }
    }
}

// ---------------- output projection GEMM (x = m0 swizzle, BK=64 panels) ------------
__global__ __launch_bounds__(256) void gemm_out_kernel(
        const u16* __restrict__ ctx, const u16* __restrict__ Wot, float* __restrict__ out) {
    __shared__ u16 As[8192];
    __shared__ u16 Bs[8192];
    const int m0 = blockIdx.x * 128, n0 = blockIdx.y * 128;
    const int tid = threadIdx.x, w = tid >> 6, lane = tid & 63;
    const int quad = lane >> 4, l16 = lane & 15;
    const int rw = w >> 1, cw = w & 1;
    const int srow = lane >> 2, sseg = lane & 3;

    f32x4 acc[4][4];
    #pragma unroll
    for (int i = 0; i < 4; i++)
        #pragma unroll
        for (int j = 0; j < 4; j++) acc[i][j] = (f32x4){0.f, 0.f, 0.f, 0.f};

    for (int kk = 0; kk < 1024; kk += 64) {
        __syncthreads();
        #pragma unroll
        for (int p = 0; p < 2; p++) {
            #pragma unroll
            for (int r = 0; r < 2; r++) {
                int base = r * 64 + w * 16;
                int row = base + srow;
                gload_lds16(&ctx[(size_t)(m0 + row) * 1024 + kk + p * 32 + sseg * 8],
                            &As[p * 4096 + base * 32]);
                gload_lds16(&Wot[(size_t)(n0 + row) * 1024 + kk + p * 32 + sseg * 8],
                            &Bs[p * 4096 + base * 32]);
            }
        }
        __syncthreads();
        #pragma unroll
        for (int p = 0; p < 2; p++) {
            bf16x8 af[4], bfr[4];
            #pragma unroll
            for (int mt = 0; mt < 4; mt++)
                af[mt] = *(const bf16x8*)&As[p * 4096 + (rw * 64 + mt * 16 + l16) * 32 + quad * 8];
            #pragma unroll
            for (int nt = 0; nt < 4; nt++)
                bfr[nt] = *(const bf16x8*)&Bs[p * 4096 + (cw * 64 + nt * 16 + l16) * 32 + quad * 8];
            #pragma unroll
            for (int mt = 0; mt < 4; mt++)
                #pragma unroll
                for (int nt = 0; nt < 4; nt++)
                    acc[mt][nt] = MFMA(af[mt], bfr[nt], acc[mt][nt]);
        }
    }

    #pragma unroll
    for (int mt = 0; mt < 4; mt++) {
        int gmBase = m0 + rw * 64 + mt * 16 + quad * 4;
        #pragma unroll
        for (int nt = 0; nt < 4; nt++) {
            int gn = n0 + cw * 64 + nt * 16 + l16;
            #pragma unroll
            for (int r = 0; r < 4; r++)
                out[(size_t)(gmBase + r) * 1024 + gn] = acc[mt][nt][r];
        }
    }
}

// ---------------- fused attention: S^T flash, 64 q-rows/wave, dbuf K/V -----------
// R5 (post-R4 budget): staged attn's dominant cost is LDS traffic — each wave
// re-read the full 8KB K-tile + 8KB V-tile per kt but owned only 32 q-rows, so one
// ds_read_b128 fed just 2 MFMA. Now each wave owns 64 q-rows (mt=4): same K/V reads
// feed 4 MFMA -> K/V LDS-read traffic per MFMA halves; K/V L2 refetch halves
// (512 blocks instead of 1024). Double-buffered K/V + T14 issue-early/write-late
// staging -> ONE barrier per kt (16 vs 32 drains). Block = 4 waves x 64 rows = 256
// q-rows; grid (128,4) = 512 blocks = exactly 2 resident/CU (LDS 56KB).
__global__ __launch_bounds__(256, 2) void attn_kernel(
        const u16* __restrict__ qb, const u16* __restrict__ kb,
        const u16* __restrict__ vb, const f32x4* __restrict__ F4,
        u16* __restrict__ ctx) {
    __shared__ u16 Kt[2][64 * 72];     // [buf][kcol][dk]  18432 B
    __shared__ u16 Vt[2][64 * 72];     // [buf][dk][scol]  18432 B
    __shared__ u16 Pt[4][64 * 40];     // per-wave P^T khalf buffer, stride 40  20480 B
    const int bh = blockIdx.x;
    const int h = bh & (NH - 1), b_ = bh >> 4;
    const int tid = threadIdx.x, w = tid >> 6, lane = tid & 63;
    const int quad = lane >> 4, l16 = lane & 15;
    const int q0 = blockIdx.y * 256 + w * 64;

    const f32x4* F4h = F4 + (size_t)h * 2047;
    // saturated-bucket constants: rel <= -91 -> bucket 15; rel >= +91 -> bucket 31
    const float cL = F4h[0][0];        // val(rel = -1023)
    const float cR = F4h[2046][0];     // val(rel = +1023)

    // Q fragments (B-operand layout): bq[mt][c] = Q[q0+mt*16+l16][c*32+quad*8 ..+7]
    bf16x8 bq[4][2];
    #pragma unroll
    for (int mt = 0; mt < 4; mt++) {
        const u16* qrow = qb + ((size_t)bh * SEQ + q0 + mt * 16 + l16) * DK;
        bq[mt][0] = *(const bf16x8*)(qrow + quad * 8);
        bq[mt][1] = *(const bf16x8*)(qrow + 32 + quad * 8);
    }

    float l_[4] = {0.f, 0.f, 0.f, 0.f};   // lane-partial row sums (this quad's k only)
    f32x4 oacc[4][4];                  // O^T frags [mt][dt]
    #pragma unroll
    for (int mt = 0; mt < 4; mt++)
        #pragma unroll
        for (int dt = 0; dt < 4; dt++) oacc[mt][dt] = (f32x4){0.f, 0.f, 0.f, 0.f};

    const int srow = tid >> 3, sseg = tid & 7;   // staging: rows srow, srow+32

    const u16* kbase_p = kb + (size_t)bh * SEQ * DK;
    const u16* vbase_p = vb + (size_t)bh * DK * SEQ;

    // staging registers (tile kt+1 in flight while computing kt)
    bf16x8 kr0, kr1, vr0, vr1;
    #define LOAD_TILE(nb)                                                        \
        kr0 = *(const bf16x8*)&kbase_p[(size_t)((nb) + srow) * DK + sseg * 8];   \
        kr1 = *(const bf16x8*)&kbase_p[(size_t)((nb) + srow + 32) * DK + sseg * 8]; \
        vr0 = *(const bf16x8*)&vbase_p[(size_t)srow * SEQ + (nb) + sseg * 8];    \
        vr1 = *(const bf16x8*)&vbase_p[(size_t)(srow + 32) * SEQ + (nb) + sseg * 8];
    #define WRITE_TILE(bi)                                                       \
        *(bf16x8*)&Kt[bi][srow * 72 + sseg * 8] = kr0;                           \
        *(bf16x8*)&Kt[bi][(srow + 32) * 72 + sseg * 8] = kr1;                    \
        *(bf16x8*)&Vt[bi][srow * 72 + sseg * 8] = vr0;                           \
        *(bf16x8*)&Vt[bi][(srow + 32) * 72 + sseg * 8] = vr1;

    // prologue: tile 0 -> buf0; issue tile 1 loads; one barrier
    LOAD_TILE(0)
    WRITE_TILE(0)
    LOAD_TILE(64)
    __syncthreads();

    for (int kt = 0; kt < 16; kt++) {
        const int kbase = kt * 64;
        const int cur = kt & 1;
        // T14 write-late: stage tile kt+1 into the other buffer, then issue kt+2
        if (kt < 15) { WRITE_TILE(cur ^ 1) }
        if (kt < 14) { LOAD_TILE(kbase + 128) }

        // S^T = K·Q^T + bias (bias via accumulator init, log2 domain)
        f32x4 sc[4][4];
        // wave-uniform far-tile test: whole 64x64 tile saturated on one side
        if (kbase <= q0 - 154 || kbase >= q0 + 154) {
            const float cc = (kbase < q0) ? cL : cR;
            #pragma unroll
            for (int mt = 0; mt < 4; mt++)
                #pragma unroll
                for (int nt = 0; nt < 4; nt++)
                    sc[mt][nt] = (f32x4){cc, cc, cc, cc};
        } else {
            #pragma unroll
            for (int mt = 0; mt < 4; mt++)
                #pragma unroll
                for (int nt = 0; nt < 4; nt++) {
                    int t0 = (kbase + nt * 16 + quad * 4) - (q0 + mt * 16 + l16) + 1023;
                    sc[mt][nt] = F4h[t0];
                }
        }

        __builtin_amdgcn_s_setprio(1);
        #pragma unroll
        for (int nt = 0; nt < 4; nt++) {
            bf16x8 ak0 = *(const bf16x8*)&Kt[cur][(nt * 16 + l16) * 72 + quad * 8];
            bf16x8 ak1 = *(const bf16x8*)&Kt[cur][(nt * 16 + l16) * 72 + 32 + quad * 8];
            #pragma unroll
            for (int mt = 0; mt < 4; mt++) {
                sc[mt][nt] = MFMA(ak0, bq[mt][0], sc[mt][nt]);
                sc[mt][nt] = MFMA(ak1, bq[mt][1], sc[mt][nt]);
            }
        }
        __builtin_amdgcn_s_setprio(0);

        // exp2, pack P^T, PV — per k-half (wave-private Pt buffer, no barriers)
        #pragma unroll
        for (int c = 0; c < 2; c++) {
            #pragma unroll
            for (int mt = 0; mt < 4; mt++) {
                #pragma unroll
                for (int i = 0; i < 2; i++) {
                    int nt = 2 * c + i;
                    float p0 = exp2_raw(sc[mt][nt][0]);
                    float p1 = exp2_raw(sc[mt][nt][1]);
                    float p2 = exp2_raw(sc[mt][nt][2]);
                    float p3 = exp2_raw(sc[mt][nt][3]);
                    l_[mt] += (p0 + p1) + (p2 + p3);
                    bf16x4 pk;
                    pk[0] = (bf16)p0; pk[1] = (bf16)p1;
                    pk[2] = (bf16)p2; pk[3] = (bf16)p3;
                    *(bf16x4*)&Pt[w][(mt * 16 + l16) * 40 + i * 16 + quad * 4] = pk;
                }
            }
            // O^T += V^T · P^T for this k-half
            bf16x8 bp[4];
            #pragma unroll
            for (int mt = 0; mt < 4; mt++)
                bp[mt] = *(const bf16x8*)&Pt[w][(mt * 16 + l16) * 40 + quad * 8];
            __builtin_amdgcn_s_setprio(1);
            #pragma unroll
            for (int dt = 0; dt < 4; dt++) {
                bf16x8 av = *(const bf16x8*)&Vt[cur][(dt * 16 + l16) * 72 + c * 32 + quad * 8];
                #pragma unroll
                for (int mt = 0; mt < 4; mt++)
                    oacc[mt][dt] = MFMA(av, bp[mt], oacc[mt][dt]);
            }
            __builtin_amdgcn_s_setprio(0);
        }
        __syncthreads();               // kt consumed + tile kt+1 staged, all waves
    }
    #undef LOAD_TILE
    #undef WRITE_TILE

    // epilogue: reduce l across quads (k-partials), normalize, write ctx
    #pragma unroll
    for (int mt = 0; mt < 4; mt++) {
        float l = l_[mt];
        l += __shfl_xor(l, 16, 64);
        l += __shfl_xor(l, 32, 64);
        float inv = 1.f / l;
        int gq = q0 + mt * 16 + l16;
        #pragma unroll
        for (int dt = 0; dt < 4; dt++) {
            u16x4 pk = { bfbits(oacc[mt][dt][0] * inv), bfbits(oacc[mt][dt][1] * inv),
                         bfbits(oacc[mt][dt][2] * inv), bfbits(oacc[mt][dt][3] * inv) };
            *(u16x4*)&ctx[((size_t)b_ * SEQ + gq) * DMODEL + h * DK + dt * 16 + quad * 4] = pk;
        }
    }
}

extern "C" void kernel_launch(void* const* d_in, const int* in_sizes, int n_in,
                              void* d_out, int out_size, void* d_ws, size_t ws_size,
                              hipStream_t stream) {
    const float* x   = (const float*)d_in[0];
    const float* Wq  = (const float*)d_in[1];
    const float* Wk  = (const float*)d_in[2];
    const float* Wv  = (const float*)d_in[3];
    const float* Wo  = (const float*)d_in[4];
    const float* rel = (const float*)d_in[5];
    float* out = (float*)d_out;

    char* p = (char*)d_ws;
    u16* xb  = (u16*)p; p += (size_t)BATCH * SEQ * DMODEL * 2;   // 16 MB
    u16* Wqt = (u16*)p; p += (size_t)DMODEL * DMODEL * 2;        // 2 MB each
    u16* Wkt = (u16*)p; p += (size_t)DMODEL * DMODEL * 2;
    u16* Wvt = (u16*)p; p += (size_t)DMODEL * DMODEL * 2;
    u16* Wot = (u16*)p; p += (size_t)DMODEL * DMODEL * 2;
    u16* qb  = (u16*)p; p += (size_t)BATCH * NH * SEQ * DK * 2;  // 16 MB each
    u16* kb  = (u16*)p; p += (size_t)BATCH * NH * SEQ * DK * 2;
    u16* vb  = (u16*)p; p += (size_t)BATCH * NH * SEQ * DK * 2;
    u16* ctx = (u16*)p; p += (size_t)BATCH * SEQ * DMODEL * 2;
    f32x4* F4 = (f32x4*)p; p += (size_t)NH * 2047 * 16;          // 0.5 MB

    // merged prep: converts + bias table in one launch
    prep_kernel<<<9344, 256, 0, stream>>>(x, Wq, Wk, Wv, Wo, rel,
                                          xb, Wqt, Wkt, Wvt, Wot, F4);

    // grid x = m0: per-XCD A-tile residency
    gemm_qkv_kernel<<<dim3(64, 24), 256, 0, stream>>>(xb, Wqt, Wkt, Wvt, qb, kb, vb);

    // 64 q-rows/wave, dbuf K/V, 1 barrier/kt; 512 blocks = 2 resident/CU
    attn_kernel<<<dim3(128, 4), 256, 0, stream>>>(qb, kb, vb, F4, ctx);

    gemm_out_kernel<<<dim3(64, 8), 256, 0, stream>>>(ctx, Wot, out);
}

// Round 6
// 234.644 us; speedup vs baseline: 1.4031x; 1.0088x over previous
//
#include <hip/hip_runtime.h>
#include <stdint.h>

typedef uint16_t u16;
typedef uint32_t u32;
typedef __bf16 bf16;
typedef bf16 bf16x8 __attribute__((ext_vector_type(8)));
typedef bf16 bf16x4 __attribute__((ext_vector_type(4)));
typedef float f32x4 __attribute__((ext_vector_type(4)));
typedef u16 u16x4 __attribute__((ext_vector_type(4)));

#define MFMA(a, b, c) __builtin_amdgcn_mfma_f32_16x16x32_bf16((a), (b), (c), 0, 0, 0)

#define BATCH 8
#define SEQ 1024
#define DMODEL 1024
#define NH 16
#define DK 64
#define LOG2E 1.4426950408889634f

// HW bf16 convert (RNE): gfx950 selects v_cvt_pk_bf16_f32 for fptrunc
__device__ __forceinline__ u16 bfbits(float f) {
    bf16 h = (bf16)f;
    return __builtin_bit_cast(u16, h);
}

// raw v_exp_f32 (args bounded |x|<~45 here; skip libm's range-guard sequence)
__device__ __forceinline__ float exp2_raw(float x) {
    float r;
    asm("v_exp_f32 %0, %1" : "=v"(r) : "v"(x));
    return r;
}

// async global->LDS, 16B per lane; LDS dst = wave-uniform base + lane*16
__device__ __forceinline__ void gload_lds16(const u16* g, u16* l) {
    __builtin_amdgcn_global_load_lds(
        (__attribute__((address_space(1))) void*)g,
        (__attribute__((address_space(3))) void*)l, 16, 0, 0);
}

// ---------------- merged prep: x->bf16, W->bf16^T, F4 bias table ----------------
// blocks [0,8192): convert x; [8192,9216): transpose-convert weights (64x64 tiles);
// [9216,9344): F4 bias. Branch is block-uniform; __syncthreads only in wt branch.
__global__ __launch_bounds__(256) void prep_kernel(
        const float* __restrict__ x, const float* __restrict__ W0,
        const float* __restrict__ W1, const float* __restrict__ W2,
        const float* __restrict__ W3, const float* __restrict__ rel_emb,
        u16* __restrict__ xb, u16* __restrict__ T0, u16* __restrict__ T1,
        u16* __restrict__ T2, u16* __restrict__ T3, f32x4* __restrict__ F4) {
    __shared__ u16 Ts[64 * 72];        // wt branch only
    const int bid = blockIdx.x, tid = threadIdx.x;
    if (bid < 8192) {
        size_t id = (size_t)bid * 256 + tid;
        f32x4 v = *(const f32x4*)(x + id * 4);
        bf16x4 o;
        o[0] = (bf16)v[0]; o[1] = (bf16)v[1]; o[2] = (bf16)v[2]; o[3] = (bf16)v[3];
        *(bf16x4*)(xb + id * 4) = o;
    } else if (bid < 9216) {
        const int t = bid - 8192;
        const int z = t >> 8, rem = t & 255;
        const float* W = (z == 0) ? W0 : (z == 1) ? W1 : (z == 2) ? W2 : W3;
        u16* T = (z == 0) ? T0 : (z == 1) ? T1 : (z == 2) ? T2 : T3;
        const int k0 = (rem >> 4) * 64, n0 = (rem & 15) * 64;
        const int r16 = tid >> 4, c0 = (tid & 15) * 4;
        #pragma unroll
        for (int rr = 0; rr < 4; rr++) {
            int r = rr * 16 + r16;     // k-row within tile
            f32x4 vv = *(const f32x4*)&W[(size_t)(k0 + r) * 1024 + n0 + c0];
            #pragma unroll
            for (int i = 0; i < 4; i++) Ts[(c0 + i) * 72 + r] = bfbits(vv[i]);
        }
        __syncthreads();
        int n = tid >> 2, seg = (tid & 3) * 16;
        *(bf16x8*)&T[(size_t)(n0 + n) * 1024 + k0 + seg] = *(const bf16x8*)&Ts[n * 72 + seg];
        *(bf16x8*)&T[(size_t)(n0 + n) * 1024 + k0 + seg + 8] =
            *(const bf16x8*)&Ts[n * 72 + seg + 8];
    } else {
        int id = (bid - 9216) * 256 + tid;
        if (id >= NH * 2047) return;
        int h = id / 2047, tt0 = id % 2047;
        f32x4 o;
        #pragma unroll
        for (int j = 0; j < 4; j++) {
            int tt = tt0 + j;
            float val = 0.f;
            if (tt <= 2046) {
                int rel = tt - 1023;
                int n = -rel;
                int b = 0;
                if (n < 0) { b = 16; n = -n; }
                int v;
                if (n < 8) {
                    v = n;
                } else {
                    int e = 31 - __clz(n);
                    int f = 2 * e + ((unsigned)(n * n) >= (1u << (2 * e + 1)) ? 1 : 0);
                    v = min(2 + f, 15);
                }
                val = LOG2E * rel_emb[(b + v) * NH + h];
            }
            o[j] = val;
        }
        F4[(size_t)h * 2047 + tt0] = o;
    }
}

// ---------------- QKV projection GEMM (R0 2-phase 128^2, known 70.4 us) ----------
// 8-phase 256^2 arc (R1/R2) abandoned: this problem's grid is 384 tiles on 256 CUs
// at 1 block/CU -> 1.5 ragged rounds (x0.75) + K=1024 short-loop overhead; measured
// 73-94 us vs this kernel's 70.4. The 2-phase 128^2 runs ~3 blocks/CU where
// cross-block wave overlap hides the barrier drains (m97/m114 mechanism).
__global__ __launch_bounds__(256) void gemm_qkv_kernel(
        const u16* __restrict__ xb,
        const u16* __restrict__ Wqt, const u16* __restrict__ Wkt, const u16* __restrict__ Wvt,
        u16* __restrict__ qb, u16* __restrict__ kb, u16* __restrict__ vb) {
    __shared__ u16 As[8192];       // 2 panels of 128x32
    __shared__ u16 Bs[8192];
    const int z = blockIdx.y >> 3;
    const u16* Bt = (z == 0) ? Wqt : (z == 1) ? Wkt : Wvt;
    const int m0 = blockIdx.x * 128, n0 = (blockIdx.y & 7) * 128;
    const int tid = threadIdx.x, w = tid >> 6, lane = tid & 63;
    const int quad = lane >> 4, l16 = lane & 15;
    const int rw = w >> 1, cw = w & 1;
    const int srow = lane >> 2, sseg = lane & 3;   // lane covers row base+srow, 16B seg

    f32x4 acc[4][4];
    #pragma unroll
    for (int i = 0; i < 4; i++)
        #pragma unroll
        for (int j = 0; j < 4; j++) acc[i][j] = (f32x4){0.f, 0.f, 0.f, 0.f};

    for (int kk = 0; kk < 1024; kk += 64) {
        __syncthreads();
        #pragma unroll
        for (int p = 0; p < 2; p++) {
            #pragma unroll
            for (int r = 0; r < 2; r++) {
                int base = r * 64 + w * 16;
                int row = base + srow;
                gload_lds16(&xb[(size_t)(m0 + row) * 1024 + kk + p * 32 + sseg * 8],
                            &As[p * 4096 + base * 32]);
                gload_lds16(&Bt[(size_t)(n0 + row) * 1024 + kk + p * 32 + sseg * 8],
                            &Bs[p * 4096 + base * 32]);
            }
        }
        __syncthreads();
        #pragma unroll
        for (int p = 0; p < 2; p++) {
            bf16x8 af[4], bfr[4];
            #pragma unroll
            for (int mt = 0; mt < 4; mt++)
                af[mt] = *(const bf16x8*)&As[p * 4096 + (rw * 64 + mt * 16 + l16) * 32 + quad * 8];
            #pragma unroll
            for (int nt = 0; nt < 4; nt++)
                bfr[nt] = *(const bf16x8*)&Bs[p * 4096 + (cw * 64 + nt * 16 + l16) * 32 + quad * 8];
            #pragma unroll
            for (int mt = 0; mt < 4; mt++)
                #pragma unroll
                for (int nt = 0; nt < 4; nt++)
                    acc[mt][nt] = MFMA(af[mt], bfr[nt], acc[mt][nt]);
        }
    }

    #pragma unroll
    for (int mt = 0; mt < 4; mt++) {
        int gmBase = m0 + rw * 64 + mt * 16 + quad * 4;
        #pragma unroll
        for (int nt = 0; nt < 4; nt++) {
            int gn = n0 + cw * 64 + nt * 16 + l16;
            int h = gn >> 6, dk = gn & 63;
            if (z == 2) {
                // V^T store: s = gmBase..+3 consecutive -> one u16x4
                int b_ = gmBase >> 10, s0 = gmBase & 1023;
                u16x4 pk = { bfbits(acc[mt][nt][0]), bfbits(acc[mt][nt][1]),
                             bfbits(acc[mt][nt][2]), bfbits(acc[mt][nt][3]) };
                *(u16x4*)&vb[(((size_t)b_ * NH + h) * DK + dk) * SEQ + s0] = pk;
            } else {
                u16* o = z ? kb : qb;
                #pragma unroll
                for (int r = 0; r < 4; r++) {
                    int gm = gmBase + r;
                    int b_ = gm >> 10, s = gm & 1023;
                    float sv = acc[mt][nt][r];
                    if (z == 0) sv *= LOG2E;       // fold exp2 scale into Q
                    o[(((size_t)b_ * NH + h) * SEQ + s) * DK + dk] = bfbits(sv);
                }
            }
        }
    }
}

// ---------------- output projection GEMM (x = m0 swizzle, BK=64 panels) ------------
__global__ __launch_bounds__(256) void gemm_out_kernel(
        const u16* __restrict__ ctx, const u16* __restrict__ Wot, float* __restrict__ out) {
    __shared__ u16 As[8192];
    __shared__ u16 Bs[8192];
    const int m0 = blockIdx.x * 128, n0 = blockIdx.y * 128;
    const int tid = threadIdx.x, w = tid >> 6, lane = tid & 63;
    const int quad = lane >> 4, l16 = lane & 15;
    const int rw = w >> 1, cw = w & 1;
    const int srow = lane >> 2, sseg = lane & 3;

    f32x4 acc[4][4];
    #pragma unroll
    for (int i = 0; i < 4; i++)
        #pragma unroll
        for (int j = 0; j < 4; j++) acc[i][j] = (f32x4){0.f, 0.f, 0.f, 0.f};

    for (int kk = 0; kk < 1024; kk += 64) {
        __syncthreads();
        #pragma unroll
        for (int p = 0; p < 2; p++) {
            #pragma unroll
            for (int r = 0; r < 2; r++) {
                int base = r * 64 + w * 16;
                int row = base + srow;
                gload_lds16(&ctx[(size_t)(m0 + row) * 1024 + kk + p * 32 + sseg * 8],
                            &As[p * 4096 + base * 32]);
                gload_lds16(&Wot[(size_t)(n0 + row) * 1024 + kk + p * 32 + sseg * 8],
                            &Bs[p * 4096 + base * 32]);
            }
        }
        __syncthreads();
        #pragma unroll
        for (int p = 0; p < 2; p++) {
            bf16x8 af[4], bfr[4];
            #pragma unroll
            for (int mt = 0; mt < 4; mt++)
                af[mt] = *(const bf16x8*)&As[p * 4096 + (rw * 64 + mt * 16 + l16) * 32 + quad * 8];
            #pragma unroll
            for (int nt = 0; nt < 4; nt++)
                bfr[nt] = *(const bf16x8*)&Bs[p * 4096 + (cw * 64 + nt * 16 + l16) * 32 + quad * 8];
            #pragma unroll
            for (int mt = 0; mt < 4; mt++)
                #pragma unroll
                for (int nt = 0; nt < 4; nt++)
                    acc[mt][nt] = MFMA(af[mt], bfr[nt], acc[mt][nt]);
        }
    }

    #pragma unroll
    for (int mt = 0; mt < 4; mt++) {
        int gmBase = m0 + rw * 64 + mt * 16 + quad * 4;
        #pragma unroll
        for (int nt = 0; nt < 4; nt++) {
            int gn = n0 + cw * 64 + nt * 16 + l16;
            #pragma unroll
            for (int r = 0; r < 4; r++)
                out[(size_t)(gmBase + r) * 1024 + gn] = acc[mt][nt][r];
        }
    }
}

// ---------------- fused attention: S^T flash, 8 waves x 64 q-rows, DMA-staged K/V --
// R6: staging moved to global_load_lds DMA (R1-proven involution swizzle: 16B slot
// index ^= row&7 on BOTH global-source and ds_read sides; conflict-free, and DMA
// removes staging ds_writes from the wave issue stream + frees 32 staging VGPRs).
// 8 waves/block (512 q-rows) -> one staged K/V tile shared 8x (global fetch halves).
// grid (128,2) = 256 blocks = exactly 1 block/CU; both q-blocks of a head on the
// same XCD (ids differ by 128 == 0 mod 8) for K/V L2 reuse. 1 barrier/kt; the
// __syncthreads implicit vmcnt(0) drain lands a full compute phase after DMA issue.
__global__ __launch_bounds__(512, 2) void attn_kernel(
        const u16* __restrict__ qb, const u16* __restrict__ kb,
        const u16* __restrict__ vb, const f32x4* __restrict__ F4,
        u16* __restrict__ ctx) {
    __shared__ u16 Kt[2][64 * 64];     // [buf][kcol][dk swizzled]  16 KiB
    __shared__ u16 Vt[2][64 * 64];     // [buf][dk][scol swizzled]  16 KiB
    __shared__ u16 Pt[8][64 * 40];     // per-wave P^T buffer, stride 40  40 KiB
    const int bh = blockIdx.x;
    const int h = bh & (NH - 1), b_ = bh >> 4;
    const int tid = threadIdx.x, w = tid >> 6, lane = tid & 63;
    const int quad = lane >> 4, l16 = lane & 15;
    const int q0 = blockIdx.y * 512 + w * 64;

    const f32x4* F4h = F4 + (size_t)h * 2047;
    // saturated-bucket constants: rel <= -91 -> bucket 15; rel >= +91 -> bucket 31
    const float cL = F4h[0][0];        // val(rel = -1023)
    const float cR = F4h[2046][0];     // val(rel = +1023)

    // Q fragments (B-operand layout): bq[mt][c] = Q[q0+mt*16+l16][c*32+quad*8 ..+7]
    bf16x8 bq[4][2];
    #pragma unroll
    for (int mt = 0; mt < 4; mt++) {
        const u16* qrow = qb + ((size_t)bh * SEQ + q0 + mt * 16 + l16) * DK;
        bq[mt][0] = *(const bf16x8*)(qrow + quad * 8);
        bq[mt][1] = *(const bf16x8*)(qrow + 32 + quad * 8);
    }

    float l_[4] = {0.f, 0.f, 0.f, 0.f};   // lane-partial row sums (this quad's k only)
    f32x4 oacc[4][4];                  // O^T frags [mt][dt]
    #pragma unroll
    for (int mt = 0; mt < 4; mt++)
        #pragma unroll
        for (int dt = 0; dt < 4; dt++) oacc[mt][dt] = (f32x4){0.f, 0.f, 0.f, 0.f};

    const u16* kbase_p = kb + (size_t)bh * SEQ * DK;
    const u16* vbase_p = vb + (size_t)bh * DK * SEQ;

    // DMA staging: thread covers tile-row w*8+(lane>>3), 16B slot lane&7.
    // Source slot = (slot ^ (row&7)) -> LDS holds slot s at data-slot s^row&7
    // (linear DMA dest, pre-swizzled source; rule 21 both-sides involution).
    const int rl = lane >> 3, slot = lane & 7;
    const int strow = w * 8 + rl, sseg = (slot ^ rl) * 8;
    #define STAGE(bi, kb0)                                                       \
        gload_lds16(&kbase_p[(size_t)((kb0) + strow) * DK + sseg],               \
                    &Kt[bi][w * 512]);                                           \
        gload_lds16(&vbase_p[(size_t)strow * SEQ + (kb0) + sseg],                \
                    &Vt[bi][w * 512]);

    // prologue: tile 0 -> buf0
    STAGE(0, 0)
    __syncthreads();                   // implicit vmcnt(0) drain (m97 behavior)

    for (int kt = 0; kt < 16; kt++) {
        const int kbase = kt * 64;
        const int cur = kt & 1;
        if (kt < 15) { STAGE(cur ^ 1, kbase + 64) }   // DMA next tile, other buffer

        // S^T = K·Q^T + bias (bias via accumulator init, log2 domain)
        f32x4 sc[4][4];
        // wave-uniform far-tile test: whole 64x64 tile saturated on one side
        if (kbase <= q0 - 154 || kbase >= q0 + 154) {
            const float cc = (kbase < q0) ? cL : cR;
            #pragma unroll
            for (int mt = 0; mt < 4; mt++)
                #pragma unroll
                for (int nt = 0; nt < 4; nt++)
                    sc[mt][nt] = (f32x4){cc, cc, cc, cc};
        } else {
            #pragma unroll
            for (int mt = 0; mt < 4; mt++)
                #pragma unroll
                for (int nt = 0; nt < 4; nt++) {
                    int t0 = (kbase + nt * 16 + quad * 4) - (q0 + mt * 16 + l16) + 1023;
                    sc[mt][nt] = F4h[t0];
                }
        }

        __builtin_amdgcn_s_setprio(1);
        #pragma unroll
        for (int nt = 0; nt < 4; nt++) {
            const int rk = nt * 16 + l16, swk = rk & 7;
            const u16* ktp = &Kt[cur][rk * 64];
            bf16x8 ak0 = *(const bf16x8*)&ktp[(quad ^ swk) * 8];
            bf16x8 ak1 = *(const bf16x8*)&ktp[((quad + 4) ^ swk) * 8];
            #pragma unroll
            for (int mt = 0; mt < 4; mt++) {
                sc[mt][nt] = MFMA(ak0, bq[mt][0], sc[mt][nt]);
                sc[mt][nt] = MFMA(ak1, bq[mt][1], sc[mt][nt]);
            }
        }
        __builtin_amdgcn_s_setprio(0);

        // exp2, pack P^T, PV — per k-half (wave-private Pt buffer, no barriers)
        #pragma unroll
        for (int c = 0; c < 2; c++) {
            #pragma unroll
            for (int mt = 0; mt < 4; mt++) {
                #pragma unroll
                for (int i = 0; i < 2; i++) {
                    int nt = 2 * c + i;
                    float p0 = exp2_raw(sc[mt][nt][0]);
                    float p1 = exp2_raw(sc[mt][nt][1]);
                    float p2 = exp2_raw(sc[mt][nt][2]);
                    float p3 = exp2_raw(sc[mt][nt][3]);
                    l_[mt] += (p0 + p1) + (p2 + p3);
                    bf16x4 pk;
                    pk[0] = (bf16)p0; pk[1] = (bf16)p1;
                    pk[2] = (bf16)p2; pk[3] = (bf16)p3;
                    *(bf16x4*)&Pt[w][(mt * 16 + l16) * 40 + i * 16 + quad * 4] = pk;
                }
            }
            // O^T += V^T · P^T for this k-half
            bf16x8 bp[4];
            #pragma unroll
            for (int mt = 0; mt < 4; mt++)
                bp[mt] = *(const bf16x8*)&Pt[w][(mt * 16 + l16) * 40 + quad * 8];
            __builtin_amdgcn_s_setprio(1);
            #pragma unroll
            for (int dt = 0; dt < 4; dt++) {
                const int rv = dt * 16 + l16;
                bf16x8 av = *(const bf16x8*)&Vt[cur][rv * 64 + (((c * 4 + quad) ^ (rv & 7)) * 8)];
                #pragma unroll
                for (int mt = 0; mt < 4; mt++)
                    oacc[mt][dt] = MFMA(av, bp[mt], oacc[mt][dt]);
            }
            __builtin_amdgcn_s_setprio(0);
        }
        if (kt < 15) __syncthreads();  // releases buf cur for overwrite; drains DMA
    }
    #undef STAGE

    // epilogue: reduce l across quads (k-partials), normalize, write ctx
    #pragma unroll
    for (int mt = 0; mt < 4; mt++) {
        float l = l_[mt];
        l += __shfl_xor(l, 16, 64);
        l += __shfl_xor(l, 32, 64);
        float inv = 1.f / l;
        int gq = q0 + mt * 16 + l16;
        #pragma unroll
        for (int dt = 0; dt < 4; dt++) {
            u16x4 pk = { bfbits(oacc[mt][dt][0] * inv), bfbits(oacc[mt][dt][1] * inv),
                         bfbits(oacc[mt][dt][2] * inv), bfbits(oacc[mt][dt][3] * inv) };
            *(u16x4*)&ctx[((size_t)b_ * SEQ + gq) * DMODEL + h * DK + dt * 16 + quad * 4] = pk;
        }
    }
}

extern "C" void kernel_launch(void* const* d_in, const int* in_sizes, int n_in,
                              void* d_out, int out_size, void* d_ws, size_t ws_size,
                              hipStream_t stream) {
    const float* x   = (const float*)d_in[0];
    const float* Wq  = (const float*)d_in[1];
    const float* Wk  = (const float*)d_in[2];
    const float* Wv  = (const float*)d_in[3];
    const float* Wo  = (const float*)d_in[4];
    const float* rel = (const float*)d_in[5];
    float* out = (float*)d_out;

    char* p = (char*)d_ws;
    u16* xb  = (u16*)p; p += (size_t)BATCH * SEQ * DMODEL * 2;   // 16 MB
    u16* Wqt = (u16*)p; p += (size_t)DMODEL * DMODEL * 2;        // 2 MB each
    u16* Wkt = (u16*)p; p += (size_t)DMODEL * DMODEL * 2;
    u16* Wvt = (u16*)p; p += (size_t)DMODEL * DMODEL * 2;
    u16* Wot = (u16*)p; p += (size_t)DMODEL * DMODEL * 2;
    u16* qb  = (u16*)p; p += (size_t)BATCH * NH * SEQ * DK * 2;  // 16 MB each
    u16* kb  = (u16*)p; p += (size_t)BATCH * NH * SEQ * DK * 2;
    u16* vb  = (u16*)p; p += (size_t)BATCH * NH * SEQ * DK * 2;
    u16* ctx = (u16*)p; p += (size_t)BATCH * SEQ * DMODEL * 2;
    f32x4* F4 = (f32x4*)p; p += (size_t)NH * 2047 * 16;          // 0.5 MB

    // merged prep: converts + bias table in one launch
    prep_kernel<<<9344, 256, 0, stream>>>(x, Wq, Wk, Wv, Wo, rel,
                                          xb, Wqt, Wkt, Wvt, Wot, F4);

    // grid x = m0: per-XCD A-tile residency
    gemm_qkv_kernel<<<dim3(64, 24), 256, 0, stream>>>(xb, Wqt, Wkt, Wvt, qb, kb, vb);

    // 8 waves x 64 q-rows, DMA-staged dbuf K/V, 1 barrier/kt; 256 blocks = 1/CU
    attn_kernel<<<dim3(128, 2), 512, 0, stream>>>(qb, kb, vb, F4, ctx);

    gemm_out_kernel<<<dim3(64, 8), 256, 0, stream>>>(ctx, Wot, out);
}

// Round 7
// 229.109 us; speedup vs baseline: 1.4370x; 1.0242x over previous
//
#include <hip/hip_runtime.h>
#include <stdint.h>

typedef uint16_t u16;
typedef uint32_t u32;
typedef __bf16 bf16;
typedef bf16 bf16x8 __attribute__((ext_vector_type(8)));
typedef bf16 bf16x4 __attribute__((ext_vector_type(4)));
typedef float f32x4 __attribute__((ext_vector_type(4)));
typedef u16 u16x4 __attribute__((ext_vector_type(4)));

#define MFMA(a, b, c) __builtin_amdgcn_mfma_f32_16x16x32_bf16((a), (b), (c), 0, 0, 0)

#define BATCH 8
#define SEQ 1024
#define DMODEL 1024
#define NH 16
#define DK 64
#define LOG2E 1.4426950408889634f

// HW bf16 convert (RNE): gfx950 selects v_cvt_pk_bf16_f32 for fptrunc
__device__ __forceinline__ u16 bfbits(float f) {
    bf16 h = (bf16)f;
    return __builtin_bit_cast(u16, h);
}

// raw v_exp_f32 (args bounded |x|<~45 here; skip libm's range-guard sequence)
__device__ __forceinline__ float exp2_raw(float x) {
    float r;
    asm("v_exp_f32 %0, %1" : "=v"(r) : "v"(x));
    return r;
}

// async global->LDS, 16B per lane; LDS dst = wave-uniform base + lane*16
__device__ __forceinline__ void gload_lds16(const u16* g, u16* l) {
    __builtin_amdgcn_global_load_lds(
        (__attribute__((address_space(1))) void*)g,
        (__attribute__((address_space(3))) void*)l, 16, 0, 0);
}

// ---------------- merged prep: x->bf16, W->bf16^T, F4 bias table ----------------
// blocks [0,8192): convert x; [8192,9216): transpose-convert weights (64x64 tiles);
// [9216,9344): F4 bias. Branch is block-uniform; __syncthreads only in wt branch.
__global__ __launch_bounds__(256) void prep_kernel(
        const float* __restrict__ x, const float* __restrict__ W0,
        const float* __restrict__ W1, const float* __restrict__ W2,
        const float* __restrict__ W3, const float* __restrict__ rel_emb,
        u16* __restrict__ xb, u16* __restrict__ T0, u16* __restrict__ T1,
        u16* __restrict__ T2, u16* __restrict__ T3, f32x4* __restrict__ F4) {
    __shared__ u16 Ts[64 * 72];        // wt branch only
    const int bid = blockIdx.x, tid = threadIdx.x;
    if (bid < 8192) {
        size_t id = (size_t)bid * 256 + tid;
        f32x4 v = *(const f32x4*)(x + id * 4);
        bf16x4 o;
        o[0] = (bf16)v[0]; o[1] = (bf16)v[1]; o[2] = (bf16)v[2]; o[3] = (bf16)v[3];
        *(bf16x4*)(xb + id * 4) = o;
    } else if (bid < 9216) {
        const int t = bid - 8192;
        const int z = t >> 8, rem = t & 255;
        const float* W = (z == 0) ? W0 : (z == 1) ? W1 : (z == 2) ? W2 : W3;
        u16* T = (z == 0) ? T0 : (z == 1) ? T1 : (z == 2) ? T2 : T3;
        const int k0 = (rem >> 4) * 64, n0 = (rem & 15) * 64;
        const int r16 = tid >> 4, c0 = (tid & 15) * 4;
        #pragma unroll
        for (int rr = 0; rr < 4; rr++) {
            int r = rr * 16 + r16;     // k-row within tile
            f32x4 vv = *(const f32x4*)&W[(size_t)(k0 + r) * 1024 + n0 + c0];
            #pragma unroll
            for (int i = 0; i < 4; i++) Ts[(c0 + i) * 72 + r] = bfbits(vv[i]);
        }
        __syncthreads();
        int n = tid >> 2, seg = (tid & 3) * 16;
        *(bf16x8*)&T[(size_t)(n0 + n) * 1024 + k0 + seg] = *(const bf16x8*)&Ts[n * 72 + seg];
        *(bf16x8*)&T[(size_t)(n0 + n) * 1024 + k0 + seg + 8] =
            *(const bf16x8*)&Ts[n * 72 + seg + 8];
    } else {
        int id = (bid - 9216) * 256 + tid;
        if (id >= NH * 2047) return;
        int h = id / 2047, tt0 = id % 2047;
        f32x4 o;
        #pragma unroll
        for (int j = 0; j < 4; j++) {
            int tt = tt0 + j;
            float val = 0.f;
            if (tt <= 2046) {
                int rel = tt - 1023;
                int n = -rel;
                int b = 0;
                if (n < 0) { b = 16; n = -n; }
                int v;
                if (n < 8) {
                    v = n;
                } else {
                    int e = 31 - __clz(n);
                    int f = 2 * e + ((unsigned)(n * n) >= (1u << (2 * e + 1)) ? 1 : 0);
                    v = min(2 + f, 15);
                }
                val = LOG2E * rel_emb[(b + v) * NH + h];
            }
            o[j] = val;
        }
        F4[(size_t)h * 2047 + tt0] = o;
    }
}

// ---------------- QKV projection GEMM: 256x128 tile, 8 waves (R7) ----------------
// Same m97 2-phase inner structure as the proven 128^2 (per-wave code and bank
// pattern identical: wave owns 64x64 via 4x4 frags, BK=64 as two 128..256x32
// panels). Changes: 768 blocks (prologue/epilogue instances halve), B global
// traffic halves, LDS 48KB -> 3 blocks/CU residency for barrier-drain hiding.
__global__ __launch_bounds__(512, 4) void gemm_qkv_kernel(
        const u16* __restrict__ xb,
        const u16* __restrict__ Wqt, const u16* __restrict__ Wkt, const u16* __restrict__ Wvt,
        u16* __restrict__ qb, u16* __restrict__ kb, u16* __restrict__ vb) {
    __shared__ u16 As[16384];      // 2 panels of 256x32
    __shared__ u16 Bs[8192];       // 2 panels of 128x32
    const int z = blockIdx.y >> 3;
    const u16* Bt = (z == 0) ? Wqt : (z == 1) ? Wkt : Wvt;
    const int m0 = blockIdx.x * 256, n0 = (blockIdx.y & 7) * 128;
    const int tid = threadIdx.x, w = tid >> 6, lane = tid & 63;
    const int quad = lane >> 4, l16 = lane & 15;
    const int wr = w >> 1, wc = w & 1;             // 4x2 wave grid, 64x64 each
    const int srow = lane >> 2, sseg = lane & 3;   // staging: 16 rows/wave, 16B segs

    f32x4 acc[4][4];
    #pragma unroll
    for (int i = 0; i < 4; i++)
        #pragma unroll
        for (int j = 0; j < 4; j++) acc[i][j] = (f32x4){0.f, 0.f, 0.f, 0.f};

    for (int kk = 0; kk < 1024; kk += 64) {
        __syncthreads();
        #pragma unroll
        for (int p = 0; p < 2; p++) {
            #pragma unroll
            for (int r = 0; r < 2; r++) {          // A: 2 chunks of 128 rows
                int base = r * 128 + w * 16;
                int row = base + srow;
                gload_lds16(&xb[(size_t)(m0 + row) * 1024 + kk + p * 32 + sseg * 8],
                            &As[p * 8192 + base * 32]);
            }
            {                                       // B: 1 chunk of 128 rows
                int base = w * 16;
                int row = base + srow;
                gload_lds16(&Bt[(size_t)(n0 + row) * 1024 + kk + p * 32 + sseg * 8],
                            &Bs[p * 4096 + base * 32]);
            }
        }
        __syncthreads();
        #pragma unroll
        for (int p = 0; p < 2; p++) {
            bf16x8 af[4], bfr[4];
            #pragma unroll
            for (int mt = 0; mt < 4; mt++)
                af[mt] = *(const bf16x8*)&As[p * 8192 + (wr * 64 + mt * 16 + l16) * 32 + quad * 8];
            #pragma unroll
            for (int nt = 0; nt < 4; nt++)
                bfr[nt] = *(const bf16x8*)&Bs[p * 4096 + (wc * 64 + nt * 16 + l16) * 32 + quad * 8];
            #pragma unroll
            for (int mt = 0; mt < 4; mt++)
                #pragma unroll
                for (int nt = 0; nt < 4; nt++)
                    acc[mt][nt] = MFMA(af[mt], bfr[nt], acc[mt][nt]);
        }
    }

    #pragma unroll
    for (int mt = 0; mt < 4; mt++) {
        int gmBase = m0 + wr * 64 + mt * 16 + quad * 4;
        #pragma unroll
        for (int nt = 0; nt < 4; nt++) {
            int gn = n0 + wc * 64 + nt * 16 + l16;
            int h = gn >> 6, dk = gn & 63;
            if (z == 2) {
                // V^T store: s = gmBase..+3 consecutive -> one u16x4
                int b_ = gmBase >> 10, s0 = gmBase & 1023;
                u16x4 pk = { bfbits(acc[mt][nt][0]), bfbits(acc[mt][nt][1]),
                             bfbits(acc[mt][nt][2]), bfbits(acc[mt][nt][3]) };
                *(u16x4*)&vb[(((size_t)b_ * NH + h) * DK + dk) * SEQ + s0] = pk;
            } else {
                u16* o = z ? kb : qb;
                #pragma unroll
                for (int r = 0; r < 4; r++) {
                    int gm = gmBase + r;
                    int b_ = gm >> 10, s = gm & 1023;
                    float sv = acc[mt][nt][r];
                    if (z == 0) sv *= LOG2E;       // fold exp2 scale into Q
                    o[(((size_t)b_ * NH + h) * SEQ + s) * DK + dk] = bfbits(sv);
                }
            }
        }
    }
}

// ---------------- output projection GEMM (x = m0 swizzle, BK=64 panels) ------------
__global__ __launch_bounds__(256) void gemm_out_kernel(
        const u16* __restrict__ ctx, const u16* __restrict__ Wot, float* __restrict__ out) {
    __shared__ u16 As[8192];
    __shared__ u16 Bs[8192];
    const int m0 = blockIdx.x * 128, n0 = blockIdx.y * 128;
    const int tid = threadIdx.x, w = tid >> 6, lane = tid & 63;
    const int quad = lane >> 4, l16 = lane & 15;
    const int rw = w >> 1, cw = w & 1;
    const int srow = lane >> 2, sseg = lane & 3;

    f32x4 acc[4][4];
    #pragma unroll
    for (int i = 0; i < 4; i++)
        #pragma unroll
        for (int j = 0; j < 4; j++) acc[i][j] = (f32x4){0.f, 0.f, 0.f, 0.f};

    for (int kk = 0; kk < 1024; kk += 64) {
        __syncthreads();
        #pragma unroll
        for (int p = 0; p < 2; p++) {
            #pragma unroll
            for (int r = 0; r < 2; r++) {
                int base = r * 64 + w * 16;
                int row = base + srow;
                gload_lds16(&ctx[(size_t)(m0 + row) * 1024 + kk + p * 32 + sseg * 8],
                            &As[p * 4096 + base * 32]);
                gload_lds16(&Wot[(size_t)(n0 + row) * 1024 + kk + p * 32 + sseg * 8],
                            &Bs[p * 4096 + base * 32]);
            }
        }
        __syncthreads();
        #pragma unroll
        for (int p = 0; p < 2; p++) {
            bf16x8 af[4], bfr[4];
            #pragma unroll
            for (int mt = 0; mt < 4; mt++)
                af[mt] = *(const bf16x8*)&As[p * 4096 + (rw * 64 + mt * 16 + l16) * 32 + quad * 8];
            #pragma unroll
            for (int nt = 0; nt < 4; nt++)
                bfr[nt] = *(const bf16x8*)&Bs[p * 4096 + (cw * 64 + nt * 16 + l16) * 32 + quad * 8];
            #pragma unroll
            for (int mt = 0; mt < 4; mt++)
                #pragma unroll
                for (int nt = 0; nt < 4; nt++)
                    acc[mt][nt] = MFMA(af[mt], bfr[nt], acc[mt][nt]);
        }
    }

    #pragma unroll
    for (int mt = 0; mt < 4; mt++) {
        int gmBase = m0 + rw * 64 + mt * 16 + quad * 4;
        #pragma unroll
        for (int nt = 0; nt < 4; nt++) {
            int gn = n0 + cw * 64 + nt * 16 + l16;
            #pragma unroll
            for (int r = 0; r < 4; r++)
                out[(size_t)(gmBase + r) * 1024 + gn] = acc[mt][nt][r];
        }
    }
}

// ---------------- fused attention: S^T flash, 4 waves x 64 q-rows, DMA K/V (R7) ----
// R5 geometry + R6 DMA staging: 4-wave blocks (barrier syncs only half the CU's
// waves -> cross-block overlap hides drains, m114) with global_load_lds swizzled
// staging (involution: 16B slot ^= row&7 on source AND ds_read; conflict-free).
// grid (128,4) = 512 blocks = 2 resident/CU (LDS 52 KB). 1 barrier/kt.
__global__ __launch_bounds__(256, 2) void attn_kernel(
        const u16* __restrict__ qb, const u16* __restrict__ kb,
        const u16* __restrict__ vb, const f32x4* __restrict__ F4,
        u16* __restrict__ ctx) {
    __shared__ u16 Kt[2][64 * 64];     // [buf][kcol][dk swizzled]  16 KiB
    __shared__ u16 Vt[2][64 * 64];     // [buf][dk][scol swizzled]  16 KiB
    __shared__ u16 Pt[4][64 * 40];     // per-wave P^T buffer, stride 40  20 KiB
    const int bh = blockIdx.x;
    const int h = bh & (NH - 1), b_ = bh >> 4;
    const int tid = threadIdx.x, w = tid >> 6, lane = tid & 63;
    const int quad = lane >> 4, l16 = lane & 15;
    const int q0 = blockIdx.y * 256 + w * 64;

    const f32x4* F4h = F4 + (size_t)h * 2047;
    // saturated-bucket constants: rel <= -91 -> bucket 15; rel >= +91 -> bucket 31
    const float cL = F4h[0][0];        // val(rel = -1023)
    const float cR = F4h[2046][0];     // val(rel = +1023)

    // Q fragments (B-operand layout): bq[mt][c] = Q[q0+mt*16+l16][c*32+quad*8 ..+7]
    bf16x8 bq[4][2];
    #pragma unroll
    for (int mt = 0; mt < 4; mt++) {
        const u16* qrow = qb + ((size_t)bh * SEQ + q0 + mt * 16 + l16) * DK;
        bq[mt][0] = *(const bf16x8*)(qrow + quad * 8);
        bq[mt][1] = *(const bf16x8*)(qrow + 32 + quad * 8);
    }

    float l_[4] = {0.f, 0.f, 0.f, 0.f};   // lane-partial row sums (this quad's k only)
    f32x4 oacc[4][4];                  // O^T frags [mt][dt]
    #pragma unroll
    for (int mt = 0; mt < 4; mt++)
        #pragma unroll
        for (int dt = 0; dt < 4; dt++) oacc[mt][dt] = (f32x4){0.f, 0.f, 0.f, 0.f};

    const u16* kbase_p = kb + (size_t)bh * SEQ * DK;
    const u16* vbase_p = vb + (size_t)bh * DK * SEQ;

    // DMA staging: 4 waves cover 64 rows as two 8-row groups per wave.
    // Source 16B slot pre-swizzled (slot ^ row&7); LDS dest linear (rule 21).
    const int rl = lane >> 3, slot = lane & 7;
    const int strow = w * 8 + rl, sseg = (slot ^ rl) * 8;
    #define STAGE(bi, kb0)                                                          \
        gload_lds16(&kbase_p[(size_t)((kb0) + strow) * DK + sseg],                  \
                    &Kt[bi][w * 512]);                                              \
        gload_lds16(&kbase_p[(size_t)((kb0) + strow + 32) * DK + sseg],             \
                    &Kt[bi][2048 + w * 512]);                                       \
        gload_lds16(&vbase_p[(size_t)strow * SEQ + (kb0) + sseg],                   \
                    &Vt[bi][w * 512]);                                              \
        gload_lds16(&vbase_p[(size_t)(strow + 32) * SEQ + (kb0) + sseg],            \
                    &Vt[bi][2048 + w * 512]);

    // prologue: tile 0 -> buf0
    STAGE(0, 0)
    __syncthreads();                   // implicit vmcnt(0) drain (m97 behavior)

    for (int kt = 0; kt < 16; kt++) {
        const int kbase = kt * 64;
        const int cur = kt & 1;
        if (kt < 15) { STAGE(cur ^ 1, kbase + 64) }   // DMA next tile, other buffer

        // S^T = K·Q^T + bias (bias via accumulator init, log2 domain)
        f32x4 sc[4][4];
        // wave-uniform far-tile test: whole 64x64 tile saturated on one side
        if (kbase <= q0 - 154 || kbase >= q0 + 154) {
            const float cc = (kbase < q0) ? cL : cR;
            #pragma unroll
            for (int mt = 0; mt < 4; mt++)
                #pragma unroll
                for (int nt = 0; nt < 4; nt++)
                    sc[mt][nt] = (f32x4){cc, cc, cc, cc};
        } else {
            #pragma unroll
            for (int mt = 0; mt < 4; mt++)
                #pragma unroll
                for (int nt = 0; nt < 4; nt++) {
                    int t0 = (kbase + nt * 16 + quad * 4) - (q0 + mt * 16 + l16) + 1023;
                    sc[mt][nt] = F4h[t0];
                }
        }

        __builtin_amdgcn_s_setprio(1);
        #pragma unroll
        for (int nt = 0; nt < 4; nt++) {
            const int rk = nt * 16 + l16, swk = rk & 7;
            const u16* ktp = &Kt[cur][rk * 64];
            bf16x8 ak0 = *(const bf16x8*)&ktp[(quad ^ swk) * 8];
            bf16x8 ak1 = *(const bf16x8*)&ktp[((quad + 4) ^ swk) * 8];
            #pragma unroll
            for (int mt = 0; mt < 4; mt++) {
                sc[mt][nt] = MFMA(ak0, bq[mt][0], sc[mt][nt]);
                sc[mt][nt] = MFMA(ak1, bq[mt][1], sc[mt][nt]);
            }
        }
        __builtin_amdgcn_s_setprio(0);

        // exp2, pack P^T, PV — per k-half (wave-private Pt buffer, no barriers)
        #pragma unroll
        for (int c = 0; c < 2; c++) {
            #pragma unroll
            for (int mt = 0; mt < 4; mt++) {
                #pragma unroll
                for (int i = 0; i < 2; i++) {
                    int nt = 2 * c + i;
                    float p0 = exp2_raw(sc[mt][nt][0]);
                    float p1 = exp2_raw(sc[mt][nt][1]);
                    float p2 = exp2_raw(sc[mt][nt][2]);
                    float p3 = exp2_raw(sc[mt][nt][3]);
                    l_[mt] += (p0 + p1) + (p2 + p3);
                    bf16x4 pk;
                    pk[0] = (bf16)p0; pk[1] = (bf16)p1;
                    pk[2] = (bf16)p2; pk[3] = (bf16)p3;
                    *(bf16x4*)&Pt[w][(mt * 16 + l16) * 40 + i * 16 + quad * 4] = pk;
                }
            }
            // O^T += V^T · P^T for this k-half
            bf16x8 bp[4];
            #pragma unroll
            for (int mt = 0; mt < 4; mt++)
                bp[mt] = *(const bf16x8*)&Pt[w][(mt * 16 + l16) * 40 + quad * 8];
            __builtin_amdgcn_s_setprio(1);
            #pragma unroll
            for (int dt = 0; dt < 4; dt++) {
                const int rv = dt * 16 + l16;
                bf16x8 av = *(const bf16x8*)&Vt[cur][rv * 64 + (((c * 4 + quad) ^ (rv & 7)) * 8)];
                #pragma unroll
                for (int mt = 0; mt < 4; mt++)
                    oacc[mt][dt] = MFMA(av, bp[mt], oacc[mt][dt]);
            }
            __builtin_amdgcn_s_setprio(0);
        }
        if (kt < 15) __syncthreads();  // releases buf cur for overwrite; drains DMA
    }
    #undef STAGE

    // epilogue: reduce l across quads (k-partials), normalize, write ctx
    #pragma unroll
    for (int mt = 0; mt < 4; mt++) {
        float l = l_[mt];
        l += __shfl_xor(l, 16, 64);
        l += __shfl_xor(l, 32, 64);
        float inv = 1.f / l;
        int gq = q0 + mt * 16 + l16;
        #pragma unroll
        for (int dt = 0; dt < 4; dt++) {
            u16x4 pk = { bfbits(oacc[mt][dt][0] * inv), bfbits(oacc[mt][dt][1] * inv),
                         bfbits(oacc[mt][dt][2] * inv), bfbits(oacc[mt][dt][3] * inv) };
            *(u16x4*)&ctx[((size_t)b_ * SEQ + gq) * DMODEL + h * DK + dt * 16 + quad * 4] = pk;
        }
    }
}

extern "C" void kernel_launch(void* const* d_in, const int* in_sizes, int n_in,
                              void* d_out, int out_size, void* d_ws, size_t ws_size,
                              hipStream_t stream) {
    const float* x   = (const float*)d_in[0];
    const float* Wq  = (const float*)d_in[1];
    const float* Wk  = (const float*)d_in[2];
    const float* Wv  = (const float*)d_in[3];
    const float* Wo  = (const float*)d_in[4];
    const float* rel = (const float*)d_in[5];
    float* out = (float*)d_out;

    char* p = (char*)d_ws;
    u16* xb  = (u16*)p; p += (size_t)BATCH * SEQ * DMODEL * 2;   // 16 MB
    u16* Wqt = (u16*)p; p += (size_t)DMODEL * DMODEL * 2;        // 2 MB each
    u16* Wkt = (u16*)p; p += (size_t)DMODEL * DMODEL * 2;
    u16* Wvt = (u16*)p; p += (size_t)DMODEL * DMODEL * 2;
    u16* Wot = (u16*)p; p += (size_t)DMODEL * DMODEL * 2;
    u16* qb  = (u16*)p; p += (size_t)BATCH * NH * SEQ * DK * 2;  // 16 MB each
    u16* kb  = (u16*)p; p += (size_t)BATCH * NH * SEQ * DK * 2;
    u16* vb  = (u16*)p; p += (size_t)BATCH * NH * SEQ * DK * 2;
    u16* ctx = (u16*)p; p += (size_t)BATCH * SEQ * DMODEL * 2;
    f32x4* F4 = (f32x4*)p; p += (size_t)NH * 2047 * 16;          // 0.5 MB

    // merged prep: converts + bias table in one launch
    prep_kernel<<<9344, 256, 0, stream>>>(x, Wq, Wk, Wv, Wo, rel,
                                          xb, Wqt, Wkt, Wvt, Wot, F4);

    // 256x128-tile 8-wave QKV GEMM: 768 blocks, 3 resident/CU
    gemm_qkv_kernel<<<dim3(32, 24), 512, 0, stream>>>(xb, Wqt, Wkt, Wvt, qb, kb, vb);

    // 4 waves x 64 q-rows, DMA-staged dbuf K/V; 512 blocks = 2 resident/CU
    attn_kernel<<<dim3(128, 4), 256, 0, stream>>>(qb, kb, vb, F4, ctx);

    gemm_out_kernel<<<dim3(64, 8), 256, 0, stream>>>(ctx, Wot, out);
}